// Round 2
// baseline (288.347 us; speedup 1.0000x reference)
//
#include <hip/hip_runtime.h>

// B,T,E,H from reference setup_inputs()
#define B_ 16
#define T_ 2048
#define E_ 1024
#define H_ 128

typedef short bf16x8 __attribute__((ext_vector_type(8)));
typedef float f32x4 __attribute__((ext_vector_type(4)));
typedef unsigned short u16x4 __attribute__((ext_vector_type(4)));

static __device__ __forceinline__ unsigned short f2bf(float f) {
    unsigned int u = __float_as_uint(f);
    u += 0x7FFFu + ((u >> 16) & 1u);   // round-to-nearest-even
    return (unsigned short)(u >> 16);
}
static __device__ __forceinline__ unsigned int pk2(unsigned short a, unsigned short b) {
    return (unsigned int)a | ((unsigned int)b << 16);
}
static __device__ __forceinline__ bf16x8 frag(uint4 v) {
    return __builtin_bit_cast(bf16x8, v);
}
// async global->LDS, 16 B per lane; LDS dest = wave-uniform base + lane*16
static __device__ __forceinline__ void gl16(const unsigned short* g, unsigned short* l) {
    __builtin_amdgcn_global_load_lds(
        (const __attribute__((address_space(1))) void*)g,
        (__attribute__((address_space(3))) void*)l, 16, 0, 0);
}

// ---------------------------------------------------------------------------
// Kernel A: W fp32->bf16 transposed to wt[n][k] (n = q|k|v rows, 0..383).
// Tiny (1.57 MB in); x is never converted — proj reads fp32 directly.
// ---------------------------------------------------------------------------
__global__ __launch_bounds__(256) void cvtw_kernel(
    const float* __restrict__ w0, const float* __restrict__ w1,
    const float* __restrict__ w2, unsigned short* __restrict__ wt)
{
    int g   = blockIdx.x * 256 + threadIdx.x;   // 0..49151
    int arr = g >> 14;
    int rem = g & 16383;
    int h   = rem >> 7;
    int e0  = (rem & 127) * 8;
    const float* src = (arr == 0) ? w0 : (arr == 1) ? w1 : w2;
    unsigned short b[8];
#pragma unroll
    for (int i = 0; i < 8; i++) b[i] = f2bf(src[(size_t)(e0 + i) * H_ + h]);
    uint4 o;
    o.x = pk2(b[0], b[1]); o.y = pk2(b[2], b[3]);
    o.z = pk2(b[4], b[5]); o.w = pk2(b[6], b[7]);
    *(uint4*)&wt[(size_t)(arr * 128 + h) * E_ + e0] = o;
}

// ---------------------------------------------------------------------------
// Kernel 1: FUSED QKV projection, 64x384 tile, 512 thr (8 waves, wave tile
// 64x48, acc[4][3]). ONLY A (x rows, shared by all 8 waves) goes through
// LDS (2 x 4KB double-buffer, reg-staged fp32->bf16, 2-step reg pipeline).
// B-fragments load DIRECTLY from wt (bf16, 0.75 MB, L2-resident) each step
// — no Bs staging, no gl16. LDS 8 KB, grid 512 -> 2 blocks/CU, 4 waves/SIMD
// (VGPR ~111 < 128 cliff). One barrier per K-step; cross-block wave overlap
// hides the barrier drain (m114 mechanism).
// ---------------------------------------------------------------------------
__global__ __launch_bounds__(512, 4) void proj_kernel(
    const float* __restrict__ x,
    const unsigned short* __restrict__ wt,
    unsigned short* __restrict__ q_ws,
    unsigned short* __restrict__ kp_ws,
    unsigned short* __restrict__ vt_ws)
{
    const int m0 = blockIdx.x * 64;
    __shared__ __align__(16) unsigned short As[2][64 * 32];

    const int tid  = threadIdx.x;
    const int lane = tid & 63;
    const int w    = tid >> 6;          // 0..7
    const int quad = lane >> 4;
    const int lm   = lane & 15;
    const int wc   = w * 48;            // wave column base (0..336)

    const int srow = tid >> 3;          // 0..63
    const int scol = (tid & 7) * 4;     // 0,4,..,28
    const float* gx = x + (size_t)(m0 + srow) * E_ + scol;
    // B-frag base: row (wc+?+lm), k-col quad*8
    const unsigned short* gb = wt + (size_t)(wc + lm) * E_ + quad * 8;

    const f32x4 z4 = {0.f, 0.f, 0.f, 0.f};
    f32x4 acc[4][3];
#pragma unroll
    for (int i = 0; i < 4; i++)
#pragma unroll
        for (int j = 0; j < 3; j++) acc[i][j] = z4;

    auto writeA = [&](float4 v, int buf) {
        u16x4 o;
        o[0] = f2bf(v.x); o[1] = f2bf(v.y);
        o[2] = f2bf(v.z); o[3] = f2bf(v.w);
        *(u16x4*)&As[buf][srow * 32 + scol] = o;
    };

    // prologue: tile 0 staged, tile 1's A in registers
    float4 a = *(const float4*)gx;          // kb=0 data
    writeA(a, 0);
    a = *(const float4*)(gx + 32);          // kb=1 data

    for (int kb = 0; kb < 32; kb++) {
        const int cb = kb & 1;
        __syncthreads();   // As[cb] published; prev compute done

        // B frags for THIS step, straight from L2 (hidden by 4-wave TLP)
        uint4 b0 = *(const uint4*)(gb + (size_t)kb * 32);
        uint4 b1 = *(const uint4*)(gb + (size_t)16 * E_ + (size_t)kb * 32);
        uint4 b2 = *(const uint4*)(gb + (size_t)32 * E_ + (size_t)kb * 32);

        // A register pipeline: prefetch kb+2, publish kb+1
        const int kb2 = (kb + 2 < 32) ? kb + 2 : 31;
        float4 n = *(const float4*)(gx + kb2 * 32);
        if (kb + 1 < 32) writeA(a, cb ^ 1);

        bf16x8 af[4];
#pragma unroll
        for (int am = 0; am < 4; am++)
            af[am] = frag(*(const uint4*)&As[cb][(am * 16 + lm) * 32 + quad * 8]);

        const bf16x8 bf0 = frag(b0), bf1 = frag(b1), bf2 = frag(b2);
#pragma unroll
        for (int am = 0; am < 4; am++) {
            acc[am][0] = __builtin_amdgcn_mfma_f32_16x16x32_bf16(af[am], bf0, acc[am][0], 0, 0, 0);
            acc[am][1] = __builtin_amdgcn_mfma_f32_16x16x32_bf16(af[am], bf1, acc[am][1], 0, 0, 0);
            acc[am][2] = __builtin_amdgcn_mfma_f32_16x16x32_bf16(af[am], bf2, acc[am][2], 0, 0, 0);
        }
        a = n;
    }

    // epilogue: route each 16-col fragment to q / kp / vt by column block
#pragma unroll
    for (int am = 0; am < 4; am++)
#pragma unroll
        for (int bn = 0; bn < 3; bn++) {
            const int gcol  = wc + bn * 16 + lm;      // 0..383 (16-aligned base)
            const int sel   = gcol >> 7;              // 0=q 1=k 2=v (wave-uniform per frag)
            const int c     = gcol & 127;
            const int rbase = m0 + am * 16 + quad * 4;
            const int bb    = rbase >> 11;
            const int t     = rbase & 2047;
            if (sel == 0) {
#pragma unroll
                for (int r = 0; r < 4; r++)
                    q_ws[(size_t)(rbase + r) * H_ + c] = f2bf(acc[am][bn][r]);
            } else if (sel == 1) {
#pragma unroll
                for (int r = 0; r < 4; r++) {
                    int tt = t + r;
                    kp_ws[(size_t)(bb * 64 + (tt >> 5)) * 4096 +
                          (c >> 5) * 1024 + (tt & 31) * 32 + (c & 31)] =
                        f2bf(acc[am][bn][r]);
                }
            } else {
                u16x4 pv;
#pragma unroll
                for (int r = 0; r < 4; r++) pv[r] = f2bf(acc[am][bn][r]);
                *(u16x4*)&vt_ws[((size_t)(bb * 64 + (t >> 5)) * 128 + c) * 32 + (t & 31)] = pv;
            }
        }
}

// ---------------------------------------------------------------------------
// Kernel 2: causal flash attention — verified inner loop, grid 512
// (2 blocks/CU, 2 waves/SIMD). Block b: batch = b&15 (XCD-local K/V:
// b%8 == batch%8), p = (b>>4)&15, tau = (b>=256) ? 31-p : p. Co-resident
// pair (b, b+256) totals exactly 68 kv-iters per CU. LDS 37 KB/block.
// NEW: T5 s_setprio(1) around the QK and PV MFMA clusters (+4-7% measured
// on attn with independent-phase waves on the CU).
// ---------------------------------------------------------------------------
__global__ __launch_bounds__(256, 2) void attn_kernel(
    const unsigned short* __restrict__ q_ws,
    const unsigned short* __restrict__ kp_ws,
    const unsigned short* __restrict__ vt_ws,
    float* __restrict__ out)
{
    __shared__ __align__(16) unsigned short Ks[2][4096];   // [h4][row32][32]
    __shared__ __align__(16) unsigned short Vs[2][4096];   // [col128][32]
    __shared__ __align__(16) unsigned short Ps[4][16][40];

    const int bid   = blockIdx.x;
    const int batch = bid & 15;
    const int p     = (bid >> 4) & 15;
    const int tau   = (bid >> 8) ? (31 - p) : p;
    const int nkt   = 2 * tau + 2;

    const int tid  = threadIdx.x;
    const int lane = tid & 63;
    const int ww   = tid >> 6;
    const int quad = lane >> 4;
    const int lm   = lane & 15;
    const float scale = 0.08838834764831845f;  // 1/sqrt(128)

    bf16x8 ones;
#pragma unroll
    for (int i = 0; i < 8; i++) ones[i] = (short)0x3F80;
    const f32x4 z4 = {0.f, 0.f, 0.f, 0.f};

    const size_t bq = (size_t)batch * T_ * H_;
    const int so = ww * 1024 + lane * 8;       // this wave's staging quarter
    const unsigned short* Kt = kp_ws + (size_t)(batch * 64) * 4096 + so;
    const unsigned short* Vt = vt_ws + (size_t)(batch * 64) * 4096 + so;

    // Q B-frags for this wave's 16 q-rows
    bf16x8 qf[4];
#pragma unroll
    for (int h = 0; h < 4; h++)
        qf[h] = frag(*(const uint4*)(q_ws + bq +
                 (size_t)(tau * 64 + ww * 16 + lm) * H_ + h * 32 + quad * 8));

    f32x4 o[9];
#pragma unroll
    for (int f = 0; f < 9; f++) o[f] = z4;

    // prologue: stage kv-tile 0 into buf 0
    gl16(Kt, &Ks[0][ww * 1024]); gl16(Kt + 512, &Ks[0][ww * 1024 + 512]);
    gl16(Vt, &Vs[0][ww * 1024]); gl16(Vt + 512, &Vs[0][ww * 1024 + 512]);

    for (int kt = 0; kt < nkt; kt++) {
        const int cb = kt & 1;
        __syncthreads();   // drains vmcnt: buf[cb] staged; prev compute done

        if (kt + 1 < nkt) {   // async stage of next tile into other buffer
            const int nb = cb ^ 1;
            const unsigned short* kg = Kt + (size_t)(kt + 1) * 4096;
            const unsigned short* vg = Vt + (size_t)(kt + 1) * 4096;
            gl16(kg, &Ks[nb][ww * 1024]); gl16(kg + 512, &Ks[nb][ww * 1024 + 512]);
            gl16(vg, &Vs[nb][ww * 1024]); gl16(vg + 512, &Vs[nb][ww * 1024 + 512]);
        }

        // S^T = K.Q^T: row = quad*4+r (kv), col = lm (q)
        f32x4 st0 = z4, st1 = z4;
        __builtin_amdgcn_s_setprio(1);
#pragma unroll
        for (int h = 0; h < 4; h++) {
            bf16x8 kf0 = frag(*(const uint4*)&Ks[cb][(h * 32 + lm) * 32 + quad * 8]);
            bf16x8 kf1 = frag(*(const uint4*)&Ks[cb][(h * 32 + 16 + lm) * 32 + quad * 8]);
            st0 = __builtin_amdgcn_mfma_f32_16x16x32_bf16(kf0, qf[h], st0, 0, 0, 0);
            st1 = __builtin_amdgcn_mfma_f32_16x16x32_bf16(kf1, qf[h], st1, 0, 0, 0);
        }
        __builtin_amdgcn_s_setprio(0);

        // mask + exp -> P in wave-private LDS (A layout [q][kv])
        const int qg = tau * 64 + ww * 16 + lm;
        const int k0 = kt * 32;
        u16x4 pa, pb;
#pragma unroll
        for (int r = 0; r < 4; r++) {
            int kv0 = k0 + quad * 4 + r;
            float e0 = __expf(st0[r] * scale);
            float e1 = __expf(st1[r] * scale);
            pa[r] = (kv0      <= qg) ? f2bf(e0) : (unsigned short)0;
            pb[r] = (kv0 + 16 <= qg) ? f2bf(e1) : (unsigned short)0;
        }
        *(u16x4*)&Ps[ww][lm][quad * 4]      = pa;
        *(u16x4*)&Ps[ww][lm][16 + quad * 4] = pb;
        bf16x8 pf = frag(*(const uint4*)&Ps[ww][lm][quad * 8]);

        // O += P.V ; l via all-ones B-frag in o[8]
        __builtin_amdgcn_s_setprio(1);
#pragma unroll
        for (int f = 0; f < 8; f++) {
            bf16x8 vfr = frag(*(const uint4*)&Vs[cb][(f * 16 + lm) * 32 + quad * 8]);
            o[f] = __builtin_amdgcn_mfma_f32_16x16x32_bf16(pf, vfr, o[f], 0, 0, 0);
        }
        o[8] = __builtin_amdgcn_mfma_f32_16x16x32_bf16(pf, ones, o[8], 0, 0, 0);
        __builtin_amdgcn_s_setprio(0);
    }

    // epilogue: divide by l, store fp32
    float* op = out + bq + (size_t)(tau * 64 + ww * 16) * H_;
#pragma unroll
    for (int r = 0; r < 4; r++) {
        float inv = 1.f / o[8][r];
#pragma unroll
        for (int f = 0; f < 8; f++)
            op[(size_t)(quad * 4 + r) * H_ + f * 16 + lm] = o[f][r] * inv;
    }
}

// ---------------------------------------------------------------------------
extern "C" void kernel_launch(void* const* d_in, const int* in_sizes, int n_in,
                              void* d_out, int out_size, void* d_ws, size_t ws_size,
                              hipStream_t stream)
{
    // setup_inputs() order: x, Wk, Wq, Wv
    const float* x  = (const float*)d_in[0];
    const float* Wk = (const float*)d_in[1];
    const float* Wq = (const float*)d_in[2];
    const float* Wv = (const float*)d_in[3];
    float* out = (float*)d_out;

    const size_t MH = (size_t)B_ * T_ * H_;        // 4,194,304
    unsigned short* q_ws  = (unsigned short*)d_ws;
    unsigned short* kp_ws = q_ws + MH;             // packed [b][kt][h][row][32]
    unsigned short* vt_ws = kp_ws + MH;            // packed [b][kt][col][32]
    unsigned short* wt    = vt_ws + MH;            // [384][1024] bf16

    cvtw_kernel<<<dim3(192), dim3(256), 0, stream>>>(Wq, Wk, Wv, wt);
    proj_kernel<<<dim3(512), dim3(512), 0, stream>>>(x, wt, q_ws, kp_ws, vt_ws);
    attn_kernel<<<dim3(512), dim3(256), 0, stream>>>(q_ws, kp_ws, vt_ws, out);
}